// Round 2
// baseline (1857.984 us; speedup 1.0000x reference)
//
#include <hip/hip_runtime.h>

// MDTA (Restormer): b=8, c=192, h=w=128, nh=8, hd=24.
// Runtime dtype probe: inputs may be fp32 (reference dtype) or bf16
// (harness-converted). probe_dtype writes flag (1=bf16) into d_ws; every
// kernel branches on it for loads; gemm_out branches for the store. Batch
// offsets are passed as ELEMENT offsets so host never needs the dtype.

#define HW 16384
#define WIMG 128
#define C 192
#define C3 576
#define NH 8
#define HD 24
#define OG 8

__device__ __forceinline__ float bfu2f(unsigned short u) {
    union { unsigned int i; float f; } v; v.i = ((unsigned int)u) << 16; return v.f;
}
__device__ __forceinline__ unsigned short f2bfu(float f) {
    union { float f; unsigned int i; } v; v.f = f;
    unsigned int x = v.i;
    return (unsigned short)((x + 0x7FFFu + ((x >> 16) & 1u)) >> 16);
}
__device__ __forceinline__ float inload(const void* p, int idx, int isbf) {
    return isbf ? bfu2f(((const unsigned short*)p)[idx]) : ((const float*)p)[idx];
}

// Decide input dtype from first 512 u32 words of x. bf16-packed: low ushort is
// an N(0,1) bf16 -> exponent field in [100,140] nearly always. fp32: low
// ushort is uniform mantissa bits -> ~16% hit rate. One block of 256.
__global__ void probe_dtype(const unsigned int* __restrict__ x, int* __restrict__ flag) {
    const int t = threadIdx.x;
    int cnt = 0;
    for (int i = t; i < 512; i += 256) {
        const unsigned int u = x[i] & 0xFFFFu;
        const unsigned int e = (u >> 7) & 0xFFu;
        if (u == 0u || (e >= 100u && e <= 140u)) cnt++;
    }
#pragma unroll
    for (int off = 32; off; off >>= 1) cnt += __shfl_down(cnt, off, 64);
    __shared__ int s[4];
    if ((t & 63) == 0) s[t >> 6] = cnt;
    __syncthreads();
    if (t == 0) flag[0] = (s[0] + s[1] + s[2] + s[3] > 300) ? 1 : 0;
}

// qkv0[o][p] = sum_c Wqkv[o][c]*x[xoff + c*HW + p].  grid (HW/512, C3/OG).
__global__ void gemm_qkv(const void* __restrict__ x, const void* __restrict__ wqkv,
                         float* __restrict__ out, const int* __restrict__ flagp,
                         size_t xoff) {
    const int isbf = flagp[0];
    __shared__ float wl[OG][C];
    const int tid = threadIdx.x;
    const int o0 = blockIdx.y * OG;
    for (int i = tid; i < OG * C; i += 256)
        wl[i / C][i % C] = inload(wqkv, (o0 + i / C) * C + (i % C), isbf);
    __syncthreads();
    const int p0 = blockIdx.x * 512 + tid * 2;
    float acc[OG][2];
#pragma unroll
    for (int j = 0; j < OG; j++) { acc[j][0] = 0.f; acc[j][1] = 0.f; }
    if (isbf) {
        const unsigned short* xp = (const unsigned short*)x + xoff;
        for (int c = 0; c < C; c++) {
            const ushort2 u = *reinterpret_cast<const ushort2*>(xp + c * HW + p0);
            const float x0 = bfu2f(u.x), x1 = bfu2f(u.y);
#pragma unroll
            for (int j = 0; j < OG; j++) {
                acc[j][0] += wl[j][c] * x0;
                acc[j][1] += wl[j][c] * x1;
            }
        }
    } else {
        const float* xp = (const float*)x + xoff;
        for (int c = 0; c < C; c++) {
            const float2 u = *reinterpret_cast<const float2*>(xp + c * HW + p0);
#pragma unroll
            for (int j = 0; j < OG; j++) {
                acc[j][0] += wl[j][c] * u.x;
                acc[j][1] += wl[j][c] * u.y;
            }
        }
    }
#pragma unroll
    for (int j = 0; j < OG; j++) {
        float* op = out + (o0 + j) * HW + p0;
        op[0] = acc[j][0]; op[1] = acc[j][1];
    }
}

// depthwise 3x3 SAME.  grid (HW/256, C3), block 256.
__global__ void dwconv(const float* __restrict__ in, const void* __restrict__ wdw,
                       float* __restrict__ out, const int* __restrict__ flagp) {
    const int isbf = flagp[0];
    const int ch = blockIdx.y;
    const int p = blockIdx.x * 256 + threadIdx.x;
    const int y = p >> 7, x = p & 127;
    const float* ip = in + ch * HW;
    float w[9];
#pragma unroll
    for (int i = 0; i < 9; i++) w[i] = inload(wdw, ch * 9 + i, isbf);
    float acc = 0.f;
#pragma unroll
    for (int ky = 0; ky < 3; ky++) {
        const int yy = y + ky - 1;
        if (yy < 0 || yy > 127) continue;
#pragma unroll
        for (int kx = 0; kx < 3; kx++) {
            const int xx = x + kx - 1;
            if (xx < 0 || xx > 127) continue;
            acc += w[ky * 3 + kx] * ip[yy * WIMG + xx];
        }
    }
    out[ch * HW + p] = acc;
}

// invnorm per q/k channel.  grid 384, block 256.
__global__ void rownorm(const float* __restrict__ qkv, float* __restrict__ invn) {
    const int row = blockIdx.x;
    const float* rp = qkv + row * HW;
    float ss = 0.f;
    for (int n = threadIdx.x; n < HW; n += 256) { const float v = rp[n]; ss += v * v; }
#pragma unroll
    for (int off = 32; off; off >>= 1) ss += __shfl_down(ss, off, 64);
    __shared__ float lds[4];
    if ((threadIdx.x & 63) == 0) lds[threadIdx.x >> 6] = ss;
    __syncthreads();
    if (threadIdx.x == 0) {
        const float t = lds[0] + lds[1] + lds[2] + lds[3];
        invn[row] = 1.f / fmaxf(sqrtf(t), 1e-12f);
    }
}

// Per (head,i): S[j] = sum_n q[i,n]k[j,n]; softmax row -> A.  grid NH*HD.
__global__ void attn_kernel(const float* __restrict__ qkv, const float* __restrict__ invn,
                            const void* __restrict__ temp, float* __restrict__ A,
                            const int* __restrict__ flagp) {
    const int isbf = flagp[0];
    const int head = blockIdx.x / HD;
    const int i = blockIdx.x % HD;
    const float* qrow = qkv + (head * HD + i) * HW;
    const float* kbase = qkv + (C + head * HD) * HW;
    float acc[HD];
#pragma unroll
    for (int j = 0; j < HD; j++) acc[j] = 0.f;
    for (int n = threadIdx.x; n < HW; n += 256) {
        const float qv = qrow[n];
#pragma unroll
        for (int j = 0; j < HD; j++) acc[j] += qv * kbase[j * HW + n];
    }
    __shared__ float lds[HD][4];
    const int lane = threadIdx.x & 63, wid = threadIdx.x >> 6;
#pragma unroll
    for (int j = 0; j < HD; j++) {
        float v = acc[j];
#pragma unroll
        for (int off = 32; off; off >>= 1) v += __shfl_down(v, off, 64);
        if (lane == 0) lds[j][wid] = v;
    }
    __syncthreads();
    if (threadIdx.x == 0) {
        float s[HD];
        const float qi = invn[head * HD + i];
        const float tp = inload(temp, head, isbf);
        float mx = -1e30f;
        for (int j = 0; j < HD; j++) {
            float d = lds[j][0] + lds[j][1] + lds[j][2] + lds[j][3];
            d *= qi * invn[C + head * HD + j] * tp;
            s[j] = d; mx = fmaxf(mx, d);
        }
        float sum = 0.f;
        for (int j = 0; j < HD; j++) { s[j] = __expf(s[j] - mx); sum += s[j]; }
        const float inv = 1.f / sum;
        for (int j = 0; j < HD; j++) A[head * HD * HD + i * HD + j] = s[j] * inv;
    }
}

// M[o][dg] = sum_c Wout[o][head*24+c] * A[head][c][d].  grid 144, block 256.
__global__ void buildM(const void* __restrict__ wout, const float* __restrict__ A,
                       float* __restrict__ M, const int* __restrict__ flagp) {
    const int isbf = flagp[0];
    const int idx = blockIdx.x * 256 + threadIdx.x;
    const int o = idx / C, dg = idx % C;
    const int head = dg / HD, d = dg % HD;
    const float* Ap = A + head * HD * HD + d;
    float acc = 0.f;
#pragma unroll
    for (int c2 = 0; c2 < HD; c2++)
        acc += inload(wout, o * C + head * HD + c2, isbf) * Ap[c2 * HD];
    M[o * C + dg] = acc;
}

// out[ooff + o*HW + p] = sum_c M[o][c]*v[c][p].  grid (HW/512, C/OG).
__global__ void gemm_out(const float* __restrict__ v, const float* __restrict__ M,
                         void* __restrict__ out, const int* __restrict__ flagp,
                         size_t ooff) {
    const int isbf = flagp[0];
    __shared__ float wl[OG][C];
    const int tid = threadIdx.x;
    const int o0 = blockIdx.y * OG;
    for (int i = tid; i < OG * C; i += 256)
        wl[i / C][i % C] = M[(o0 + i / C) * C + (i % C)];
    __syncthreads();
    const int p0 = blockIdx.x * 512 + tid * 2;
    float acc[OG][2];
#pragma unroll
    for (int j = 0; j < OG; j++) { acc[j][0] = 0.f; acc[j][1] = 0.f; }
    for (int c = 0; c < C; c++) {
        const float2 xv = *reinterpret_cast<const float2*>(v + c * HW + p0);
#pragma unroll
        for (int j = 0; j < OG; j++) {
            acc[j][0] += wl[j][c] * xv.x;
            acc[j][1] += wl[j][c] * xv.y;
        }
    }
    if (isbf) {
        unsigned short* op = (unsigned short*)out + ooff;
#pragma unroll
        for (int j = 0; j < OG; j++) {
            const unsigned int pk = (unsigned int)f2bfu(acc[j][0]) |
                                    ((unsigned int)f2bfu(acc[j][1]) << 16);
            *reinterpret_cast<unsigned int*>(op + (o0 + j) * HW + p0) = pk;
        }
    } else {
        float* op = (float*)out + ooff;
#pragma unroll
        for (int j = 0; j < OG; j++) {
            float2 st; st.x = acc[j][0]; st.y = acc[j][1];
            *reinterpret_cast<float2*>(op + (o0 + j) * HW + p0) = st;
        }
    }
}

extern "C" void kernel_launch(void* const* d_in, const int* in_sizes, int n_in,
                              void* d_out, int out_size, void* d_ws, size_t ws_size,
                              hipStream_t stream) {
    const void* x    = d_in[0];
    const void* wqkv = d_in[1];
    const void* wdw  = d_in[2];
    const void* wout = d_in[3];
    const void* temp = d_in[4];

    int* flag = (int*)d_ws;
    float* base = (float*)d_ws + 16;
    float* qkv0 = base;                        // 576*16384
    float* qkv1 = qkv0 + (size_t)C3 * HW;      // 576*16384
    float* invn = qkv1 + (size_t)C3 * HW;      // 384
    float* A    = invn + 384;                  // 8*24*24
    float* M    = A + NH * HD * HD;            // 192*192

    probe_dtype<<<1, 256, 0, stream>>>((const unsigned int*)x, flag);

    for (int b = 0; b < 8; b++) {
        const size_t off = (size_t)b * C * HW;  // element offset
        gemm_qkv<<<dim3(HW / 512, C3 / OG), 256, 0, stream>>>(x, wqkv, qkv0, flag, off);
        dwconv<<<dim3(HW / 256, C3), 256, 0, stream>>>(qkv0, wdw, qkv1, flag);
        rownorm<<<dim3(2 * C), 256, 0, stream>>>(qkv1, invn);
        attn_kernel<<<dim3(NH * HD), 256, 0, stream>>>(qkv1, invn, temp, A, flag);
        buildM<<<dim3(C * C / 256), 256, 0, stream>>>(wout, A, M, flag);
        gemm_out<<<dim3(HW / 512, C / OG), 256, 0, stream>>>(qkv1 + (size_t)2 * C * HW, M, d_out, flag, off);
    }
}

// Round 3
// 1086.015 us; speedup vs baseline: 1.7108x; 1.7108x over previous
//
#include <hip/hip_runtime.h>

// MDTA (Restormer): b=8, c=192, h=w=128, nh=8, hd=24.
// Round 3: bf16 MFMA for both K=192 GEMMs, bf16 intermediates, fused epilogues.
// Per batch: gemm_mfma(qkv) -> dwconv -> rownorm -> attn_partial -> buildM(softmax fused) -> gemm_mfma(out).
// Runtime dtype probe (flag in ws) handles fp32-vs-bf16 harness inputs.

#define HW 16384
#define WIMG 128
#define C 192
#define C3 576
#define NH 8
#define HD 24
#define NSPLIT 32
#define CHUNK 512

typedef unsigned short ushort8_t __attribute__((ext_vector_type(8)));
typedef unsigned short ushort4_t __attribute__((ext_vector_type(4)));
typedef short short8_t __attribute__((ext_vector_type(8)));
typedef float float4_t __attribute__((ext_vector_type(4)));

__device__ __forceinline__ float bfu2f(unsigned short u) {
    union { unsigned int i; float f; } v; v.i = ((unsigned int)u) << 16; return v.f;
}
__device__ __forceinline__ unsigned short f2bfu(float f) {
    union { float f; unsigned int i; } v; v.f = f;
    unsigned int x = v.i;
    return (unsigned short)((x + 0x7FFFu + ((x >> 16) & 1u)) >> 16);
}
__device__ __forceinline__ float inload(const void* p, int idx, int isbf) {
    return isbf ? bfu2f(((const unsigned short*)p)[idx]) : ((const float*)p)[idx];
}

// dtype probe: bf16-packed x -> low ushort of u32 is an N(0,1) bf16 (exp in
// [100,140]); fp32 x -> low ushort is uniform mantissa bits (~16% hit).
__global__ void probe_dtype(const unsigned int* __restrict__ x, int* __restrict__ flag) {
    const int t = threadIdx.x;
    int cnt = 0;
    for (int i = t; i < 512; i += 256) {
        const unsigned int u = x[i] & 0xFFFFu;
        const unsigned int e = (u >> 7) & 0xFFu;
        if (u == 0u || (e >= 100u && e <= 140u)) cnt++;
    }
#pragma unroll
    for (int off = 32; off; off >>= 1) cnt += __shfl_down(cnt, off, 64);
    __shared__ int s[4];
    if ((t & 63) == 0) s[t >> 6] = cnt;
    __syncthreads();
    if (t == 0) flag[0] = (s[0] + s[1] + s[2] + s[3] > 300) ? 1 : 0;
}

// Convert weights once per call; zero the all-batch Sraw accumulator.
__global__ void prep(const void* __restrict__ wqkv, const void* __restrict__ wdw,
                     const void* __restrict__ wout, const void* __restrict__ temp,
                     const int* __restrict__ flagp, unsigned short* __restrict__ wqb,
                     float* __restrict__ wdwf, float* __restrict__ woutf,
                     float* __restrict__ tempf, float* __restrict__ Sraw) {
    const int isbf = flagp[0];
    const int id = blockIdx.x * 256 + threadIdx.x;
    const int stride = gridDim.x * 256;
    for (int i = id; i < C3 * C; i += stride)
        wqb[i] = isbf ? ((const unsigned short*)wqkv)[i] : f2bfu(((const float*)wqkv)[i]);
    for (int i = id; i < C3 * 9; i += stride) wdwf[i] = inload(wdw, i, isbf);
    for (int i = id; i < C * C; i += stride) woutf[i] = inload(wout, i, isbf);
    for (int i = id; i < NH; i += stride) tempf[i] = inload(temp, i, isbf);
    for (int i = id; i < 8 * NH * HD * HD; i += stride) Sraw[i] = 0.f;
}

// GEMM via MFMA 16x16x32 bf16.  out[M x HW] = A[M x 192] * B[192 x HW].
// grid (HW/128, M/64), block 512 (8 waves). B staged transposed in LDS as
// 8-elem k-chunks: chunk(p, cg) at index p*24 + (cg ^ (p&7))  (XOR swizzle ->
// conflict-free ds_read_b128 on fragment reads).
// b_mode: 0 = B dtype per flag (x input), 1 = B always bf16 (workspace).
// out_mode: 0 = store bf16 (workspace), 1 = store per flag dtype (d_out).
__global__ __launch_bounds__(512) void gemm_mfma(
    const void* __restrict__ Bsrc, const unsigned short* __restrict__ Abf,
    void* __restrict__ outp, const int* __restrict__ flagp,
    size_t b_off, size_t o_off, int b_mode, int out_mode) {
    __shared__ unsigned short xT[24576];  // 3072 chunks * 8 bf16 = 48 KB
    const int isbf = flagp[0];
    const int b_isbf = b_mode | isbf;
    const int tid = threadIdx.x;
    const int n0 = blockIdx.x * 128;
    const int m0 = blockIdx.y * 64;

    // ---- stage B tile [192 x 128] -> LDS (transposed via in-register 8x8) ----
    if (tid < 384) {
        const int cg = tid >> 4;   // [0,24) : c-chunk of 8
        const int pg = tid & 15;   // [0,16) : pixel-group of 8
        ushort8_t rows[8];
        if (b_isbf) {
            const unsigned short* bp = (const unsigned short*)Bsrc + b_off + n0 + pg * 8;
#pragma unroll
            for (int r = 0; r < 8; r++)
                rows[r] = *reinterpret_cast<const ushort8_t*>(bp + (size_t)(cg * 8 + r) * HW);
        } else {
            const float* bp = (const float*)Bsrc + b_off + n0 + pg * 8;
#pragma unroll
            for (int r = 0; r < 8; r++) {
                const float4_t f0 = *reinterpret_cast<const float4_t*>(bp + (size_t)(cg * 8 + r) * HW);
                const float4_t f1 = *reinterpret_cast<const float4_t*>(bp + (size_t)(cg * 8 + r) * HW + 4);
#pragma unroll
                for (int i = 0; i < 4; i++) { rows[r][i] = f2bfu(f0[i]); rows[r][i + 4] = f2bfu(f1[i]); }
            }
        }
#pragma unroll
        for (int s = 0; s < 8; s++) {
            ushort8_t outv;
#pragma unroll
            for (int r = 0; r < 8; r++) outv[r] = rows[r][s];
            const int p = pg * 8 + s;
            const int cidx = p * 24 + (cg ^ (p & 7));
            *reinterpret_cast<ushort8_t*>(&xT[cidx * 8]) = outv;
        }
    }

    // ---- A fragments: lane holds A[m = lane&15][k = quad*8 + j] ----
    const int w = tid >> 6;
    const int lane = tid & 63;
    const int l15 = lane & 15;
    const int quad = lane >> 4;
    const int mhalf = w & 1;   // m-tiles {mhalf*2, mhalf*2+1}
    const int nquad = w >> 1;  // pixels nquad*32 + {0,16}

    short8_t afr[2][6];
#pragma unroll
    for (int mt = 0; mt < 2; mt++) {
        const int row = m0 + (mhalf * 2 + mt) * 16 + l15;
#pragma unroll
        for (int ks = 0; ks < 6; ks++)
            afr[mt][ks] = *reinterpret_cast<const short8_t*>(Abf + (size_t)row * C + ks * 32 + quad * 8);
    }

    float4_t acc[2][2];
#pragma unroll
    for (int mt = 0; mt < 2; mt++)
#pragma unroll
        for (int nt = 0; nt < 2; nt++) {
            float4_t z = {0.f, 0.f, 0.f, 0.f};
            acc[mt][nt] = z;
        }

    __syncthreads();

#pragma unroll
    for (int ks = 0; ks < 6; ks++) {
        short8_t bfr[2];
#pragma unroll
        for (int nt = 0; nt < 2; nt++) {
            const int p = nquad * 32 + nt * 16 + l15;
            const int cg = ks * 4 + quad;
            const int cidx = p * 24 + (cg ^ (p & 7));
            bfr[nt] = *reinterpret_cast<const short8_t*>(&xT[cidx * 8]);
        }
#pragma unroll
        for (int mt = 0; mt < 2; mt++)
#pragma unroll
            for (int nt = 0; nt < 2; nt++)
                acc[mt][nt] = __builtin_amdgcn_mfma_f32_16x16x32_bf16(
                    afr[mt][ks], bfr[nt], acc[mt][nt], 0, 0, 0);
    }

    // ---- store: D[row = quad*4 + reg][col = lane&15] ----
    const int o_isbf = out_mode ? isbf : 1;
#pragma unroll
    for (int mt = 0; mt < 2; mt++) {
        const int row = m0 + (mhalf * 2 + mt) * 16 + quad * 4;
#pragma unroll
        for (int nt = 0; nt < 2; nt++) {
            const int col = n0 + nquad * 32 + nt * 16 + l15;
#pragma unroll
            for (int r = 0; r < 4; r++) {
                const size_t idx = o_off + (size_t)(row + r) * HW + col;
                if (o_isbf) ((unsigned short*)outp)[idx] = f2bfu(acc[mt][nt][r]);
                else ((float*)outp)[idx] = acc[mt][nt][r];
            }
        }
    }
}

// depthwise 3x3 SAME, bf16 in/out, fp32 math.  grid (64, 576), block 256.
__global__ void dwconv(const unsigned short* __restrict__ in,
                       const float* __restrict__ wdwf,
                       unsigned short* __restrict__ out) {
    const int ch = blockIdx.y;
    const int p = blockIdx.x * 256 + threadIdx.x;
    const int y = p >> 7, x = p & 127;
    const unsigned short* ip = in + (size_t)ch * HW;
    const float* wp = wdwf + ch * 9;
    float acc = 0.f;
#pragma unroll
    for (int ky = 0; ky < 3; ky++) {
        const int yy = y + ky - 1;
        if (yy < 0 || yy > 127) continue;
#pragma unroll
        for (int kx = 0; kx < 3; kx++) {
            const int xx = x + kx - 1;
            if (xx < 0 || xx > 127) continue;
            acc += wp[ky * 3 + kx] * bfu2f(ip[yy * WIMG + xx]);
        }
    }
    out[(size_t)ch * HW + p] = f2bfu(acc);
}

// invnorm per q/k channel (bf16 reads).  grid 384, block 256.
__global__ void rownorm(const unsigned short* __restrict__ qkv, float* __restrict__ invn) {
    const int row = blockIdx.x;
    const unsigned short* rp = qkv + (size_t)row * HW;
    float ss = 0.f;
    for (int n = threadIdx.x * 4; n < HW; n += 1024) {
        const ushort4_t u = *reinterpret_cast<const ushort4_t*>(rp + n);
#pragma unroll
        for (int i = 0; i < 4; i++) { const float v = bfu2f(u[i]); ss += v * v; }
    }
#pragma unroll
    for (int off = 32; off; off >>= 1) ss += __shfl_down(ss, off, 64);
    __shared__ float lds[4];
    if ((threadIdx.x & 63) == 0) lds[threadIdx.x >> 6] = ss;
    __syncthreads();
    if (threadIdx.x == 0) {
        const float t = lds[0] + lds[1] + lds[2] + lds[3];
        invn[row] = 1.f / fmaxf(sqrtf(t), 1e-12f);
    }
}

// Raw Gram partials: Sraw[h][i][j] += q_i . k_j over an n-chunk.
// grid (NH*NSPLIT), block 576 (thread = (i,j)).
__global__ void attn_partial(const unsigned short* __restrict__ qkv1,
                             float* __restrict__ Sraw) {
    const int h = blockIdx.x >> 5;
    const int sp = blockIdx.x & 31;
    const int t = threadIdx.x;
    const int i = t / HD, j = t % HD;
    const int n0 = sp * CHUNK;
    const unsigned short* qp = qkv1 + (size_t)(h * HD + i) * HW + n0;
    const unsigned short* kp = qkv1 + (size_t)(C + h * HD + j) * HW + n0;
    float acc = 0.f;
    for (int n = 0; n < CHUNK; n += 4) {
        const ushort4_t qu = *reinterpret_cast<const ushort4_t*>(qp + n);
        const ushort4_t ku = *reinterpret_cast<const ushort4_t*>(kp + n);
#pragma unroll
        for (int e = 0; e < 4; e++) acc += bfu2f(qu[e]) * bfu2f(ku[e]);
    }
    atomicAdd(&Sraw[(h * HD + i) * HD + j], acc);
}

// Fused softmax + M = Wout * blockdiag(A), bf16 store.  grid 144, block 256.
__global__ void buildM(const float* __restrict__ Sraw, const float* __restrict__ invn,
                       const float* __restrict__ tempf, const float* __restrict__ woutf,
                       unsigned short* __restrict__ Mb) {
    __shared__ float As[NH * HD * HD];
    const int tid = threadIdx.x;
    // scale raw scores
    for (int e = tid; e < NH * HD * HD; e += 256) {
        const int h = e / (HD * HD);
        const int rem = e - h * HD * HD;
        const int i = rem / HD, j = rem % HD;
        As[e] = Sraw[e] * invn[h * HD + i] * invn[C + h * HD + j] * tempf[h];
    }
    __syncthreads();
    // row-wise softmax (192 rows)
    if (tid < C) {
        const int h = tid / HD, i = tid % HD;
        float* rp = As + h * HD * HD + i * HD;
        float mx = -1e30f;
#pragma unroll
        for (int j = 0; j < HD; j++) mx = fmaxf(mx, rp[j]);
        float sum = 0.f;
#pragma unroll
        for (int j = 0; j < HD; j++) { rp[j] = __expf(rp[j] - mx); sum += rp[j]; }
        const float inv = 1.f / sum;
#pragma unroll
        for (int j = 0; j < HD; j++) rp[j] *= inv;
    }
    __syncthreads();
    // M[o][h*24+d] = sum_c Wout[o][h*24+c] * A[h][c][d]
    const int idx = blockIdx.x * 256 + tid;
    const int o = idx / C, dg = idx % C;
    const int h = dg / HD, d = dg % HD;
    const float* wp = woutf + o * C + h * HD;
    const float* Ap = As + h * HD * HD + d;
    float acc = 0.f;
#pragma unroll
    for (int c2 = 0; c2 < HD; c2++) acc += wp[c2] * Ap[c2 * HD];
    Mb[o * C + dg] = f2bfu(acc);
}

extern "C" void kernel_launch(void* const* d_in, const int* in_sizes, int n_in,
                              void* d_out, int out_size, void* d_ws, size_t ws_size,
                              hipStream_t stream) {
    const void* x    = d_in[0];
    const void* wqkv = d_in[1];
    const void* wdw  = d_in[2];
    const void* wout = d_in[3];
    const void* temp = d_in[4];

    char* w = (char*)d_ws;
    int* flag = (int*)w;                          w += 64;
    unsigned short* wqb = (unsigned short*)w;     w += (size_t)C3 * C * 2;
    unsigned short* Mb  = (unsigned short*)w;     w += (size_t)C * C * 2;
    float* wdwf  = (float*)w;                     w += (size_t)C3 * 9 * 4 + 48; // pad to 16B
    float* woutf = (float*)w;                     w += (size_t)C * C * 4;
    float* tempf = (float*)w;                     w += 64;
    float* invn  = (float*)w;                     w += 384 * 4;
    float* Sraw  = (float*)w;                     w += (size_t)8 * NH * HD * HD * 4;
    unsigned short* qkv0 = (unsigned short*)w;    w += (size_t)C3 * HW * 2;
    unsigned short* qkv1 = (unsigned short*)w;

    probe_dtype<<<1, 256, 0, stream>>>((const unsigned int*)x, flag);
    prep<<<432, 256, 0, stream>>>(wqkv, wdw, wout, temp, flag, wqb, wdwf, woutf, tempf, Sraw);

    for (int b = 0; b < 8; b++) {
        const size_t off = (size_t)b * C * HW;
        // qkv0 = Wqkv @ x_b   (bf16 out)
        gemm_mfma<<<dim3(HW / 128, C3 / 64), 512, 0, stream>>>(
            x, wqb, qkv0, flag, off, 0, /*b_mode=*/0, /*out_mode=*/0);
        dwconv<<<dim3(64, C3), 256, 0, stream>>>(qkv0, wdwf, qkv1);
        rownorm<<<384, 256, 0, stream>>>(qkv1, invn);
        attn_partial<<<NH * NSPLIT, 576, 0, stream>>>(qkv1, Sraw + (size_t)b * NH * HD * HD);
        buildM<<<144, 256, 0, stream>>>(Sraw + (size_t)b * NH * HD * HD, invn, tempf, woutf, Mb);
        // out_b = M @ v   (dtype per flag)
        gemm_mfma<<<dim3(HW / 128, C / 64), 512, 0, stream>>>(
            qkv1, Mb, d_out, flag, /*b_off=*/(size_t)2 * C * HW, /*o_off=*/off,
            /*b_mode=*/1, /*out_mode=*/1);
    }
}

// Round 4
// 614.957 us; speedup vs baseline: 3.0213x; 1.7660x over previous
//
#include <hip/hip_runtime.h>

// MDTA (Restormer): b=8, c=192, h=w=128, nh=8, hd=24.
// Round 4: all stages batch-fused (7 dispatches/call), m-loop inside MFMA GEMM
// (B tile staged once, B-frags in registers), rownorm folded into attn_partial,
// dwconv vectorized 8px/thread. Runtime dtype probe handles fp32/bf16 inputs.

#define HW 16384
#define WIMG 128
#define C 192
#define C3 576
#define NH 8
#define HD 24
#define NSPLIT 32
#define CHUNK 512

typedef unsigned short ushort8_t __attribute__((ext_vector_type(8)));
typedef unsigned short ushort4_t __attribute__((ext_vector_type(4)));
typedef short short8_t __attribute__((ext_vector_type(8)));
typedef float float4_t __attribute__((ext_vector_type(4)));

__device__ __forceinline__ float bfu2f(unsigned short u) {
    union { unsigned int i; float f; } v; v.i = ((unsigned int)u) << 16; return v.f;
}
__device__ __forceinline__ unsigned short f2bfu(float f) {
    union { float f; unsigned int i; } v; v.f = f;
    unsigned int x = v.i;
    return (unsigned short)((x + 0x7FFFu + ((x >> 16) & 1u)) >> 16);
}
__device__ __forceinline__ float inload(const void* p, int idx, int isbf) {
    return isbf ? bfu2f(((const unsigned short*)p)[idx]) : ((const float*)p)[idx];
}

// dtype probe: bf16-packed x -> low ushort of u32 is an N(0,1) bf16 (exp in
// [100,140]); fp32 x -> low ushort is uniform mantissa bits (~16% hit).
__global__ void probe_dtype(const unsigned int* __restrict__ x, int* __restrict__ flag) {
    const int t = threadIdx.x;
    int cnt = 0;
    for (int i = t; i < 512; i += 256) {
        const unsigned int u = x[i] & 0xFFFFu;
        const unsigned int e = (u >> 7) & 0xFFu;
        if (u == 0u || (e >= 100u && e <= 140u)) cnt++;
    }
#pragma unroll
    for (int off = 32; off; off >>= 1) cnt += __shfl_down(cnt, off, 64);
    __shared__ int s[4];
    if ((t & 63) == 0) s[t >> 6] = cnt;
    __syncthreads();
    if (t == 0) flag[0] = (s[0] + s[1] + s[2] + s[3] > 300) ? 1 : 0;
}

// Convert weights once; zero Sraw + normsum accumulators (ws is re-poisoned
// 0xAA before every timed call, so this must run every call).
__global__ void prep(const void* __restrict__ wqkv, const void* __restrict__ wdw,
                     const void* __restrict__ wout, const void* __restrict__ temp,
                     const int* __restrict__ flagp, unsigned short* __restrict__ wqb,
                     float* __restrict__ wdwf, float* __restrict__ woutf,
                     float* __restrict__ tempf, float* __restrict__ Sraw,
                     float* __restrict__ normsum) {
    const int isbf = flagp[0];
    const int id = blockIdx.x * 256 + threadIdx.x;
    const int stride = gridDim.x * 256;
    for (int i = id; i < C3 * C; i += stride)
        wqb[i] = isbf ? ((const unsigned short*)wqkv)[i] : f2bfu(((const float*)wqkv)[i]);
    for (int i = id; i < C3 * 9; i += stride) wdwf[i] = inload(wdw, i, isbf);
    for (int i = id; i < C * C; i += stride) woutf[i] = inload(wout, i, isbf);
    for (int i = id; i < NH; i += stride) tempf[i] = inload(temp, i, isbf);
    for (int i = id; i < 8 * NH * HD * HD; i += stride) Sraw[i] = 0.f;
    for (int i = id; i < 8 * 2 * C; i += stride) normsum[i] = 0.f;
}

// GEMM via MFMA 16x16x32 bf16: out[m_tiles*64 x HW] = A[. x 192] * B[192 x HW],
// batched over blockIdx.y. B tile [192x128] staged once in LDS (transposed via
// in-register 8x8, XOR-swizzled chunks -> conflict-free ds_read_b128); B-frags
// preloaded to registers; inner loop over m-tiles only loads A-frags + MFMA.
// b_mode: 0 = B dtype per flag, 1 = B always bf16. out_mode: 0 = bf16 store,
// 1 = store per flag dtype.
__global__ __launch_bounds__(512) void gemm_mfma(
    const void* __restrict__ Bsrc, const unsigned short* __restrict__ Abf,
    void* __restrict__ outp, const int* __restrict__ flagp,
    size_t b_batch_stride, size_t b_const_off, size_t o_batch_stride,
    int a_batch_stride, int m_tiles, int b_mode, int out_mode) {
    __shared__ unsigned short xT[24576];  // 3072 chunks * 8 bf16 = 48 KB
    const int isbf = flagp[0];
    const int b_isbf = b_mode | isbf;
    const int tid = threadIdx.x;
    const int batch = blockIdx.y;
    const int n0 = blockIdx.x * 128;
    const size_t b_off = b_batch_stride * batch + b_const_off;
    const size_t o_off = o_batch_stride * batch;
    const unsigned short* Ab = Abf + (size_t)a_batch_stride * batch;

    // ---- stage B tile [192 x 128] -> LDS ----
    if (tid < 384) {
        const int cg = tid >> 4;   // [0,24) c-chunk of 8
        const int pg = tid & 15;   // [0,16) pixel-group of 8
        ushort8_t rows[8];
        if (b_isbf) {
            const unsigned short* bp = (const unsigned short*)Bsrc + b_off + n0 + pg * 8;
#pragma unroll
            for (int r = 0; r < 8; r++)
                rows[r] = *reinterpret_cast<const ushort8_t*>(bp + (size_t)(cg * 8 + r) * HW);
        } else {
            const float* bp = (const float*)Bsrc + b_off + n0 + pg * 8;
#pragma unroll
            for (int r = 0; r < 8; r++) {
                const float4_t f0 = *reinterpret_cast<const float4_t*>(bp + (size_t)(cg * 8 + r) * HW);
                const float4_t f1 = *reinterpret_cast<const float4_t*>(bp + (size_t)(cg * 8 + r) * HW + 4);
#pragma unroll
                for (int i = 0; i < 4; i++) { rows[r][i] = f2bfu(f0[i]); rows[r][i + 4] = f2bfu(f1[i]); }
            }
        }
#pragma unroll
        for (int s = 0; s < 8; s++) {
            ushort8_t outv;
#pragma unroll
            for (int r = 0; r < 8; r++) outv[r] = rows[r][s];
            const int p = pg * 8 + s;
            const int cidx = p * 24 + (cg ^ (p & 7));
            *reinterpret_cast<ushort8_t*>(&xT[cidx * 8]) = outv;
        }
    }

    const int w = tid >> 6;
    const int lane = tid & 63;
    const int l15 = lane & 15;
    const int quad = lane >> 4;
    const int mhalf = w & 1;
    const int nquad = w >> 1;

    __syncthreads();

    // ---- preload B fragments (reused across all m-tiles) ----
    short8_t bfr[6][2];
#pragma unroll
    for (int ks = 0; ks < 6; ks++)
#pragma unroll
        for (int nt = 0; nt < 2; nt++) {
            const int p = nquad * 32 + nt * 16 + l15;
            const int cg = ks * 4 + quad;
            const int cidx = p * 24 + (cg ^ (p & 7));
            bfr[ks][nt] = *reinterpret_cast<const short8_t*>(&xT[cidx * 8]);
        }

    const int o_isbf = out_mode ? isbf : 1;
    for (int mt0 = 0; mt0 < m_tiles; mt0++) {
        const int m0 = mt0 * 64;
        short8_t afr[2][6];
#pragma unroll
        for (int mt = 0; mt < 2; mt++) {
            const int row = m0 + (mhalf * 2 + mt) * 16 + l15;
#pragma unroll
            for (int ks = 0; ks < 6; ks++)
                afr[mt][ks] = *reinterpret_cast<const short8_t*>(Ab + (size_t)row * C + ks * 32 + quad * 8);
        }
        float4_t acc[2][2];
#pragma unroll
        for (int mt = 0; mt < 2; mt++)
#pragma unroll
            for (int nt = 0; nt < 2; nt++) {
                float4_t z = {0.f, 0.f, 0.f, 0.f};
                acc[mt][nt] = z;
            }
#pragma unroll
        for (int ks = 0; ks < 6; ks++)
#pragma unroll
            for (int mt = 0; mt < 2; mt++)
#pragma unroll
                for (int nt = 0; nt < 2; nt++)
                    acc[mt][nt] = __builtin_amdgcn_mfma_f32_16x16x32_bf16(
                        afr[mt][ks], bfr[ks][nt], acc[mt][nt], 0, 0, 0);
        // store: D[row = quad*4 + reg][col = lane&15]
#pragma unroll
        for (int mt = 0; mt < 2; mt++) {
            const int row = m0 + (mhalf * 2 + mt) * 16 + quad * 4;
#pragma unroll
            for (int nt = 0; nt < 2; nt++) {
                const int col = n0 + nquad * 32 + nt * 16 + l15;
#pragma unroll
                for (int r = 0; r < 4; r++) {
                    const size_t idx = o_off + (size_t)(row + r) * HW + col;
                    if (o_isbf) ((unsigned short*)outp)[idx] = f2bfu(acc[mt][nt][r]);
                    else ((float*)outp)[idx] = acc[mt][nt][r];
                }
            }
        }
    }
}

// depthwise 3x3 SAME, bf16 in/out, fp32 math, 8 px/thread.
// grid (8, 576, 8): x = 2048-px slab, y = channel, z = batch.  block 256.
__global__ void dwconv(const unsigned short* __restrict__ qkv0,
                       const float* __restrict__ wdwf,
                       unsigned short* __restrict__ qkv1) {
    const int ch = blockIdx.y;
    const size_t base = (size_t)blockIdx.z * C3 * HW + (size_t)ch * HW;
    const unsigned short* ip = qkv0 + base;
    const float* wp = wdwf + ch * 9;
    const int p = blockIdx.x * 2048 + threadIdx.x * 8;
    const int y = p >> 7, x0 = p & 127;
    float acc[8];
#pragma unroll
    for (int j = 0; j < 8; j++) acc[j] = 0.f;
#pragma unroll
    for (int dy = 0; dy < 3; dy++) {
        const int yy = y + dy - 1;
        if (yy < 0 || yy > 127) continue;
        const int rb = yy * WIMG + x0;
        const ushort8_t mid = *reinterpret_cast<const ushort8_t*>(ip + rb);
        float f[10];
        f[0] = (x0 > 0) ? bfu2f(ip[rb - 1]) : 0.f;
        f[9] = (x0 < 120) ? bfu2f(ip[rb + 8]) : 0.f;
#pragma unroll
        for (int i = 0; i < 8; i++) f[i + 1] = bfu2f(mid[i]);
        const float w0 = wp[dy * 3], w1 = wp[dy * 3 + 1], w2 = wp[dy * 3 + 2];
#pragma unroll
        for (int j = 0; j < 8; j++) acc[j] += w0 * f[j] + w1 * f[j + 1] + w2 * f[j + 2];
    }
    ushort8_t outv;
#pragma unroll
    for (int j = 0; j < 8; j++) outv[j] = f2bfu(acc[j]);
    *reinterpret_cast<ushort8_t*>(qkv1 + base + p) = outv;
}

// Gram partials + q/k self-norm partials.  grid (8*NH*NSPLIT = 2048), block 640.
// Threads [0,576): (i,j) -> Sraw[h][i][j] += q_i . k_j over chunk.
// Threads [576,600): q_i self-dot -> normsum[b][h*HD+i].
// Threads [600,624): k_j self-dot -> normsum[b][192 + h*HD+j].
__global__ __launch_bounds__(640) void attn_partial(
    const unsigned short* __restrict__ qkv1, float* __restrict__ Sraw,
    float* __restrict__ normsum) {
    const int b = blockIdx.x >> 8;
    const int rem = blockIdx.x & 255;
    const int h = rem >> 5;
    const int sp = rem & 31;
    const int n0 = sp * CHUNK;
    const unsigned short* qb = qkv1 + (size_t)b * C3 * HW;
    const int t = threadIdx.x;
    if (t < 576) {
        const int i = t / HD, j = t % HD;
        const unsigned short* qp = qb + (size_t)(h * HD + i) * HW + n0;
        const unsigned short* kp = qb + (size_t)(C + h * HD + j) * HW + n0;
        float acc = 0.f;
        for (int n = 0; n < CHUNK; n += 4) {
            const ushort4_t qu = *reinterpret_cast<const ushort4_t*>(qp + n);
            const ushort4_t ku = *reinterpret_cast<const ushort4_t*>(kp + n);
#pragma unroll
            for (int e = 0; e < 4; e++) acc += bfu2f(qu[e]) * bfu2f(ku[e]);
        }
        atomicAdd(&Sraw[(size_t)b * NH * HD * HD + (h * HD + i) * HD + j], acc);
    } else if (t < 624) {
        const int isq = (t < 600) ? 1 : 0;
        const int i = t - (isq ? 576 : 600);
        const unsigned short* rp = qb + (size_t)((isq ? 0 : C) + h * HD + i) * HW + n0;
        float acc = 0.f;
        for (int n = 0; n < CHUNK; n += 4) {
            const ushort4_t u = *reinterpret_cast<const ushort4_t*>(rp + n);
#pragma unroll
            for (int e = 0; e < 4; e++) { const float v = bfu2f(u[e]); acc += v * v; }
        }
        atomicAdd(&normsum[b * 2 * C + (isq ? 0 : C) + h * HD + i], acc);
    }
}

// Fused invnorm + softmax + M = Wout * blockdiag(A), bf16.  grid (144, 8).
__global__ void buildM(const float* __restrict__ Sraw, const float* __restrict__ normsum,
                       const float* __restrict__ tempf, const float* __restrict__ woutf,
                       unsigned short* __restrict__ Mb) {
    __shared__ float As[NH * HD * HD];
    __shared__ float inv[2 * C];
    const int b = blockIdx.y;
    const int tid = threadIdx.x;
    for (int r = tid; r < 2 * C; r += 256)
        inv[r] = 1.f / fmaxf(sqrtf(normsum[b * 2 * C + r]), 1e-12f);
    __syncthreads();
    for (int e = tid; e < NH * HD * HD; e += 256) {
        const int h = e / (HD * HD);
        const int rm = e - h * HD * HD;
        const int i = rm / HD, j = rm % HD;
        As[e] = Sraw[(size_t)b * NH * HD * HD + e] * inv[h * HD + i] * inv[C + h * HD + j] * tempf[h];
    }
    __syncthreads();
    if (tid < C) {
        const int h = tid / HD, i = tid % HD;
        float* rp = As + h * HD * HD + i * HD;
        float mx = -1e30f;
#pragma unroll
        for (int j = 0; j < HD; j++) mx = fmaxf(mx, rp[j]);
        float sum = 0.f;
#pragma unroll
        for (int j = 0; j < HD; j++) { rp[j] = __expf(rp[j] - mx); sum += rp[j]; }
        const float is = 1.f / sum;
#pragma unroll
        for (int j = 0; j < HD; j++) rp[j] *= is;
    }
    __syncthreads();
    const int idx = blockIdx.x * 256 + tid;
    const int o = idx / C, dg = idx % C;
    const int h = dg / HD, d = dg % HD;
    const float* wp = woutf + o * C + h * HD;
    const float* Ap = As + h * HD * HD + d;
    float acc = 0.f;
#pragma unroll
    for (int c2 = 0; c2 < HD; c2++) acc += wp[c2] * Ap[c2 * HD];
    Mb[(size_t)b * C * C + o * C + dg] = f2bfu(acc);
}

extern "C" void kernel_launch(void* const* d_in, const int* in_sizes, int n_in,
                              void* d_out, int out_size, void* d_ws, size_t ws_size,
                              hipStream_t stream) {
    const void* x    = d_in[0];
    const void* wqkv = d_in[1];
    const void* wdw  = d_in[2];
    const void* wout = d_in[3];
    const void* temp = d_in[4];

    char* w = (char*)d_ws;
    int* flag = (int*)w;                          w += 64;
    unsigned short* wqb = (unsigned short*)w;     w += (size_t)C3 * C * 2;       // 221184
    unsigned short* Mb  = (unsigned short*)w;     w += (size_t)8 * C * C * 2;    // 589824
    float* wdwf  = (float*)w;                     w += (size_t)C3 * 9 * 4;       // 20736
    float* woutf = (float*)w;                     w += (size_t)C * C * 4;        // 147456
    float* tempf = (float*)w;                     w += 64;
    float* normsum = (float*)w;                   w += (size_t)8 * 2 * C * 4;    // 12288
    float* Sraw  = (float*)w;                     w += (size_t)8 * NH * HD * HD * 4; // 147456
    unsigned short* qkv0 = (unsigned short*)w;    w += (size_t)8 * C3 * HW * 2;  // 151 MB
    unsigned short* qkv1 = (unsigned short*)w;    // 151 MB

    probe_dtype<<<1, 256, 0, stream>>>((const unsigned int*)x, flag);
    prep<<<432, 256, 0, stream>>>(wqkv, wdw, wout, temp, flag, wqb, wdwf, woutf,
                                  tempf, Sraw, normsum);
    // qkv0[b] = Wqkv @ x_b  (bf16 out, 9 m-tiles)
    gemm_mfma<<<dim3(HW / 128, 8), 512, 0, stream>>>(
        x, wqb, qkv0, flag, (size_t)C * HW, 0, (size_t)C3 * HW, 0, 9, 0, 0);
    dwconv<<<dim3(8, C3, 8), 256, 0, stream>>>(qkv0, wdwf, qkv1);
    attn_partial<<<2048, 640, 0, stream>>>(qkv1, Sraw, normsum);
    buildM<<<dim3(144, 8), 256, 0, stream>>>(Sraw, normsum, tempf, woutf, Mb);
    // out_b = M_b @ v_b  (dtype per flag, 3 m-tiles)
    gemm_mfma<<<dim3(HW / 128, 8), 512, 0, stream>>>(
        qkv1, Mb, d_out, flag, (size_t)C3 * HW, (size_t)2 * C * HW, (size_t)C * HW,
        C * C, 3, 1, 1);
}

// Round 5
// 455.876 us; speedup vs baseline: 4.0756x; 1.3490x over previous
//
#include <hip/hip_runtime.h>

// MDTA (Restormer): b=8, c=192, h=w=128, nh=8, hd=24.
// Round 5: attn Gram via MFMA (was latency-bound scalar, 200 us); q/k norm
// sums fused into dwconv epilogue (fp32 pre-store values). 7 dispatches/call.
// Runtime dtype probe handles fp32-vs-bf16 harness inputs.

#define HW 16384
#define WIMG 128
#define C 192
#define C3 576
#define NH 8
#define HD 24

typedef unsigned short ushort8_t __attribute__((ext_vector_type(8)));
typedef unsigned short ushort4_t __attribute__((ext_vector_type(4)));
typedef short short8_t __attribute__((ext_vector_type(8)));
typedef float float4_t __attribute__((ext_vector_type(4)));

__device__ __forceinline__ float bfu2f(unsigned short u) {
    union { unsigned int i; float f; } v; v.i = ((unsigned int)u) << 16; return v.f;
}
__device__ __forceinline__ unsigned short f2bfu(float f) {
    union { float f; unsigned int i; } v; v.f = f;
    unsigned int x = v.i;
    return (unsigned short)((x + 0x7FFFu + ((x >> 16) & 1u)) >> 16);
}
__device__ __forceinline__ float inload(const void* p, int idx, int isbf) {
    return isbf ? bfu2f(((const unsigned short*)p)[idx]) : ((const float*)p)[idx];
}

// dtype probe: bf16-packed x -> low ushort of u32 is an N(0,1) bf16 (exp in
// [100,140]); fp32 x -> low ushort is uniform mantissa bits (~16% hit).
__global__ void probe_dtype(const unsigned int* __restrict__ x, int* __restrict__ flag) {
    const int t = threadIdx.x;
    int cnt = 0;
    for (int i = t; i < 512; i += 256) {
        const unsigned int u = x[i] & 0xFFFFu;
        const unsigned int e = (u >> 7) & 0xFFu;
        if (u == 0u || (e >= 100u && e <= 140u)) cnt++;
    }
#pragma unroll
    for (int off = 32; off; off >>= 1) cnt += __shfl_down(cnt, off, 64);
    __shared__ int s[4];
    if ((t & 63) == 0) s[t >> 6] = cnt;
    __syncthreads();
    if (t == 0) flag[0] = (s[0] + s[1] + s[2] + s[3] > 300) ? 1 : 0;
}

// Convert weights once; zero Sraw + normsum accumulators (ws is re-poisoned
// 0xAA before every timed call, so this must run every call).
__global__ void prep(const void* __restrict__ wqkv, const void* __restrict__ wdw,
                     const void* __restrict__ wout, const void* __restrict__ temp,
                     const int* __restrict__ flagp, unsigned short* __restrict__ wqb,
                     float* __restrict__ wdwf, float* __restrict__ woutf,
                     float* __restrict__ tempf, float* __restrict__ Sraw,
                     float* __restrict__ normsum) {
    const int isbf = flagp[0];
    const int id = blockIdx.x * 256 + threadIdx.x;
    const int stride = gridDim.x * 256;
    for (int i = id; i < C3 * C; i += stride)
        wqb[i] = isbf ? ((const unsigned short*)wqkv)[i] : f2bfu(((const float*)wqkv)[i]);
    for (int i = id; i < C3 * 9; i += stride) wdwf[i] = inload(wdw, i, isbf);
    for (int i = id; i < C * C; i += stride) woutf[i] = inload(wout, i, isbf);
    for (int i = id; i < NH; i += stride) tempf[i] = inload(temp, i, isbf);
    for (int i = id; i < 8 * NH * HD * HD; i += stride) Sraw[i] = 0.f;
    for (int i = id; i < 8 * 2 * C; i += stride) normsum[i] = 0.f;
}

// GEMM via MFMA 16x16x32 bf16: out[m_tiles*64 x HW] = A[. x 192] * B[192 x HW],
// batched over blockIdx.y. B tile [192x128] staged once in LDS (transposed via
// in-register 8x8, XOR-swizzled chunks -> conflict-free ds_read_b128); B-frags
// preloaded to registers; inner loop over m-tiles only loads A-frags + MFMA.
__global__ __launch_bounds__(512) void gemm_mfma(
    const void* __restrict__ Bsrc, const unsigned short* __restrict__ Abf,
    void* __restrict__ outp, const int* __restrict__ flagp,
    size_t b_batch_stride, size_t b_const_off, size_t o_batch_stride,
    int a_batch_stride, int m_tiles, int b_mode, int out_mode) {
    __shared__ unsigned short xT[24576];  // 3072 chunks * 8 bf16 = 48 KB
    const int isbf = flagp[0];
    const int b_isbf = b_mode | isbf;
    const int tid = threadIdx.x;
    const int batch = blockIdx.y;
    const int n0 = blockIdx.x * 128;
    const size_t b_off = b_batch_stride * batch + b_const_off;
    const size_t o_off = o_batch_stride * batch;
    const unsigned short* Ab = Abf + (size_t)a_batch_stride * batch;

    if (tid < 384) {
        const int cg = tid >> 4;   // [0,24) c-chunk of 8
        const int pg = tid & 15;   // [0,16) pixel-group of 8
        ushort8_t rows[8];
        if (b_isbf) {
            const unsigned short* bp = (const unsigned short*)Bsrc + b_off + n0 + pg * 8;
#pragma unroll
            for (int r = 0; r < 8; r++)
                rows[r] = *reinterpret_cast<const ushort8_t*>(bp + (size_t)(cg * 8 + r) * HW);
        } else {
            const float* bp = (const float*)Bsrc + b_off + n0 + pg * 8;
#pragma unroll
            for (int r = 0; r < 8; r++) {
                const float4_t f0 = *reinterpret_cast<const float4_t*>(bp + (size_t)(cg * 8 + r) * HW);
                const float4_t f1 = *reinterpret_cast<const float4_t*>(bp + (size_t)(cg * 8 + r) * HW + 4);
#pragma unroll
                for (int i = 0; i < 4; i++) { rows[r][i] = f2bfu(f0[i]); rows[r][i + 4] = f2bfu(f1[i]); }
            }
        }
#pragma unroll
        for (int s = 0; s < 8; s++) {
            ushort8_t outv;
#pragma unroll
            for (int r = 0; r < 8; r++) outv[r] = rows[r][s];
            const int p = pg * 8 + s;
            const int cidx = p * 24 + (cg ^ (p & 7));
            *reinterpret_cast<ushort8_t*>(&xT[cidx * 8]) = outv;
        }
    }

    const int w = tid >> 6;
    const int lane = tid & 63;
    const int l15 = lane & 15;
    const int quad = lane >> 4;
    const int mhalf = w & 1;
    const int nquad = w >> 1;

    __syncthreads();

    short8_t bfr[6][2];
#pragma unroll
    for (int ks = 0; ks < 6; ks++)
#pragma unroll
        for (int nt = 0; nt < 2; nt++) {
            const int p = nquad * 32 + nt * 16 + l15;
            const int cg = ks * 4 + quad;
            const int cidx = p * 24 + (cg ^ (p & 7));
            bfr[ks][nt] = *reinterpret_cast<const short8_t*>(&xT[cidx * 8]);
        }

    const int o_isbf = out_mode ? isbf : 1;
    for (int mt0 = 0; mt0 < m_tiles; mt0++) {
        const int m0 = mt0 * 64;
        short8_t afr[2][6];
#pragma unroll
        for (int mt = 0; mt < 2; mt++) {
            const int row = m0 + (mhalf * 2 + mt) * 16 + l15;
#pragma unroll
            for (int ks = 0; ks < 6; ks++)
                afr[mt][ks] = *reinterpret_cast<const short8_t*>(Ab + (size_t)row * C + ks * 32 + quad * 8);
        }
        float4_t acc[2][2];
#pragma unroll
        for (int mt = 0; mt < 2; mt++)
#pragma unroll
            for (int nt = 0; nt < 2; nt++) {
                float4_t z = {0.f, 0.f, 0.f, 0.f};
                acc[mt][nt] = z;
            }
#pragma unroll
        for (int ks = 0; ks < 6; ks++)
#pragma unroll
            for (int mt = 0; mt < 2; mt++)
#pragma unroll
                for (int nt = 0; nt < 2; nt++)
                    acc[mt][nt] = __builtin_amdgcn_mfma_f32_16x16x32_bf16(
                        afr[mt][ks], bfr[ks][nt], acc[mt][nt], 0, 0, 0);
#pragma unroll
        for (int mt = 0; mt < 2; mt++) {
            const int row = m0 + (mhalf * 2 + mt) * 16 + quad * 4;
#pragma unroll
            for (int nt = 0; nt < 2; nt++) {
                const int col = n0 + nquad * 32 + nt * 16 + l15;
#pragma unroll
                for (int r = 0; r < 4; r++) {
                    const size_t idx = o_off + (size_t)(row + r) * HW + col;
                    if (o_isbf) ((unsigned short*)outp)[idx] = f2bfu(acc[mt][nt][r]);
                    else ((float*)outp)[idx] = acc[mt][nt][r];
                }
            }
        }
    }
}

// depthwise 3x3 SAME, bf16 in/out, fp32 math, 8 px/thread; q/k channel
// norm-sums accumulated from fp32 pre-store values (one atomic per block).
// grid (8, 576, 8): x = 2048-px slab, y = channel, z = batch.  block 256.
__global__ void dwconv(const unsigned short* __restrict__ qkv0,
                       const float* __restrict__ wdwf,
                       unsigned short* __restrict__ qkv1,
                       float* __restrict__ normsum) {
    const int ch = blockIdx.y;
    const size_t base = (size_t)blockIdx.z * C3 * HW + (size_t)ch * HW;
    const unsigned short* ip = qkv0 + base;
    const float* wp = wdwf + ch * 9;
    const int p = blockIdx.x * 2048 + threadIdx.x * 8;
    const int y = p >> 7, x0 = p & 127;
    float acc[8];
#pragma unroll
    for (int j = 0; j < 8; j++) acc[j] = 0.f;
#pragma unroll
    for (int dy = 0; dy < 3; dy++) {
        const int yy = y + dy - 1;
        if (yy < 0 || yy > 127) continue;
        const int rb = yy * WIMG + x0;
        const ushort8_t mid = *reinterpret_cast<const ushort8_t*>(ip + rb);
        float f[10];
        f[0] = (x0 > 0) ? bfu2f(ip[rb - 1]) : 0.f;
        f[9] = (x0 < 120) ? bfu2f(ip[rb + 8]) : 0.f;
#pragma unroll
        for (int i = 0; i < 8; i++) f[i + 1] = bfu2f(mid[i]);
        const float w0 = wp[dy * 3], w1 = wp[dy * 3 + 1], w2 = wp[dy * 3 + 2];
#pragma unroll
        for (int j = 0; j < 8; j++) acc[j] += w0 * f[j] + w1 * f[j + 1] + w2 * f[j + 2];
    }
    ushort8_t outv;
#pragma unroll
    for (int j = 0; j < 8; j++) outv[j] = f2bfu(acc[j]);
    *reinterpret_cast<ushort8_t*>(qkv1 + base + p) = outv;

    if (ch < 2 * C) {  // q or k channel: accumulate sum of squares
        float ss = 0.f;
#pragma unroll
        for (int j = 0; j < 8; j++) ss += acc[j] * acc[j];
#pragma unroll
        for (int off = 32; off; off >>= 1) ss += __shfl_down(ss, off, 64);
        __shared__ float red[4];
        if ((threadIdx.x & 63) == 0) red[threadIdx.x >> 6] = ss;
        __syncthreads();
        if (threadIdx.x == 0)
            atomicAdd(&normsum[blockIdx.z * 2 * C + ch],
                      red[0] + red[1] + red[2] + red[3]);
    }
}

// Gram S[h] = Q(24xHW) . K^T via MFMA on padded 32x32 tiles.
// grid (8, NH, 8): x = split-group (4 waves -> 32 k-splits of 512), y = h,
// z = b.  block 256 = 4 waves; one wave per k-split; atomicAdd into Sraw.
// Padding rows (24..31) read the adjacent channels in the same batch slab
// (always in-bounds); their products land in discarded tile entries.
__global__ __launch_bounds__(256) void attn_gram(
    const unsigned short* __restrict__ qkv1, float* __restrict__ Sraw) {
    const int b = blockIdx.z, h = blockIdx.y;
    const int wave = threadIdx.x >> 6;
    const int lane = threadIdx.x & 63;
    const int l15 = lane & 15, quad = lane >> 4;
    const int k0 = (blockIdx.x * 4 + wave) * 512;
    const unsigned short* qrow = qkv1 + (size_t)b * C3 * HW + (size_t)(h * HD) * HW;
    const unsigned short* krow = qkv1 + (size_t)b * C3 * HW + (size_t)(C + h * HD) * HW;

    float4_t acc[2][2];
#pragma unroll
    for (int mt = 0; mt < 2; mt++)
#pragma unroll
        for (int nt = 0; nt < 2; nt++) {
            float4_t z = {0.f, 0.f, 0.f, 0.f};
            acc[mt][nt] = z;
        }

#pragma unroll 4
    for (int ks = 0; ks < 16; ks++) {
        const int kk = k0 + ks * 32 + quad * 8;
        short8_t qa[2], kb[2];
        qa[0] = *reinterpret_cast<const short8_t*>(qrow + (size_t)l15 * HW + kk);
        qa[1] = *reinterpret_cast<const short8_t*>(qrow + (size_t)(16 + l15) * HW + kk);
        kb[0] = *reinterpret_cast<const short8_t*>(krow + (size_t)l15 * HW + kk);
        kb[1] = *reinterpret_cast<const short8_t*>(krow + (size_t)(16 + l15) * HW + kk);
#pragma unroll
        for (int mt = 0; mt < 2; mt++)
#pragma unroll
            for (int nt = 0; nt < 2; nt++)
                acc[mt][nt] = __builtin_amdgcn_mfma_f32_16x16x32_bf16(
                    qa[mt], kb[nt], acc[mt][nt], 0, 0, 0);
    }

    float* Sb = Sraw + (size_t)b * NH * HD * HD + (size_t)h * HD * HD;
#pragma unroll
    for (int nt = 0; nt < 2; nt++) {
        const int j = nt * 16 + l15;
        if (j >= HD) continue;
#pragma unroll
        for (int mt = 0; mt < 2; mt++) {
            const int i0 = mt * 16 + quad * 4;
#pragma unroll
            for (int r = 0; r < 4; r++) {
                const int i = i0 + r;
                if (i < HD) atomicAdd(&Sb[i * HD + j], acc[mt][nt][r]);
            }
        }
    }
}

// Fused invnorm + softmax + M = Wout * blockdiag(A), bf16.  grid (144, 8).
__global__ void buildM(const float* __restrict__ Sraw, const float* __restrict__ normsum,
                       const float* __restrict__ tempf, const float* __restrict__ woutf,
                       unsigned short* __restrict__ Mb) {
    __shared__ float As[NH * HD * HD];
    __shared__ float inv[2 * C];
    const int b = blockIdx.y;
    const int tid = threadIdx.x;
    for (int r = tid; r < 2 * C; r += 256)
        inv[r] = 1.f / fmaxf(sqrtf(normsum[b * 2 * C + r]), 1e-12f);
    __syncthreads();
    for (int e = tid; e < NH * HD * HD; e += 256) {
        const int h = e / (HD * HD);
        const int rm = e - h * HD * HD;
        const int i = rm / HD, j = rm % HD;
        As[e] = Sraw[(size_t)b * NH * HD * HD + e] * inv[h * HD + i] * inv[C + h * HD + j] * tempf[h];
    }
    __syncthreads();
    if (tid < C) {
        const int h = tid / HD, i = tid % HD;
        float* rp = As + h * HD * HD + i * HD;
        float mx = -1e30f;
#pragma unroll
        for (int j = 0; j < HD; j++) mx = fmaxf(mx, rp[j]);
        float sum = 0.f;
#pragma unroll
        for (int j = 0; j < HD; j++) { rp[j] = __expf(rp[j] - mx); sum += rp[j]; }
        const float is = 1.f / sum;
#pragma unroll
        for (int j = 0; j < HD; j++) rp[j] *= is;
    }
    __syncthreads();
    const int idx = blockIdx.x * 256 + tid;
    const int o = idx / C, dg = idx % C;
    const int h = dg / HD, d = dg % HD;
    const float* wp = woutf + o * C + h * HD;
    const float* Ap = As + h * HD * HD + d;
    float acc = 0.f;
#pragma unroll
    for (int c2 = 0; c2 < HD; c2++) acc += wp[c2] * Ap[c2 * HD];
    Mb[(size_t)b * C * C + o * C + dg] = f2bfu(acc);
}

extern "C" void kernel_launch(void* const* d_in, const int* in_sizes, int n_in,
                              void* d_out, int out_size, void* d_ws, size_t ws_size,
                              hipStream_t stream) {
    const void* x    = d_in[0];
    const void* wqkv = d_in[1];
    const void* wdw  = d_in[2];
    const void* wout = d_in[3];
    const void* temp = d_in[4];

    char* w = (char*)d_ws;
    int* flag = (int*)w;                          w += 64;
    unsigned short* wqb = (unsigned short*)w;     w += (size_t)C3 * C * 2;
    unsigned short* Mb  = (unsigned short*)w;     w += (size_t)8 * C * C * 2;
    float* wdwf  = (float*)w;                     w += (size_t)C3 * 9 * 4;
    float* woutf = (float*)w;                     w += (size_t)C * C * 4;
    float* tempf = (float*)w;                     w += 64;
    float* normsum = (float*)w;                   w += (size_t)8 * 2 * C * 4;
    float* Sraw  = (float*)w;                     w += (size_t)8 * NH * HD * HD * 4;
    unsigned short* qkv0 = (unsigned short*)w;    w += (size_t)8 * C3 * HW * 2;
    unsigned short* qkv1 = (unsigned short*)w;

    probe_dtype<<<1, 256, 0, stream>>>((const unsigned int*)x, flag);
    prep<<<432, 256, 0, stream>>>(wqkv, wdw, wout, temp, flag, wqb, wdwf, woutf,
                                  tempf, Sraw, normsum);
    // qkv0[b] = Wqkv @ x_b  (bf16 out, 9 m-tiles)
    gemm_mfma<<<dim3(HW / 128, 8), 512, 0, stream>>>(
        x, wqb, qkv0, flag, (size_t)C * HW, 0, (size_t)C3 * HW, 0, 9, 0, 0);
    dwconv<<<dim3(8, C3, 8), 256, 0, stream>>>(qkv0, wdwf, qkv1, normsum);
    attn_gram<<<dim3(8, NH, 8), 256, 0, stream>>>(qkv1, Sraw);
    buildM<<<dim3(144, 8), 256, 0, stream>>>(Sraw, normsum, tempf, woutf, Mb);
    // out_b = M_b @ v_b  (dtype per flag, 3 m-tiles)
    gemm_mfma<<<dim3(HW / 128, 8), 512, 0, stream>>>(
        qkv1, Mb, d_out, flag, (size_t)C3 * HW, (size_t)2 * C * HW, (size_t)C * HW,
        C * C, 3, 1, 1);
}